// Round 16
// baseline (61.586 us; speedup 1.0000x reference)
//
#include <hip/hip_runtime.h>

#define CIN 16
#define COUT 32
#define NB 8
#define HW 4096
#define PPW 66                 // padded image width
#define KF 160                 // features per pixel: 16ch * 10 (silu, T1..T8, zero)
#define NCH 20                 // 16B chunks per pixel (KF/8)
#define FROWS 6                // feature rows per block (4 output rows + halo)

typedef short bf16x8 __attribute__((ext_vector_type(8)));
typedef float f32x4 __attribute__((ext_vector_type(4)));

__device__ inline unsigned short f2bf(float f) {
    unsigned u = __builtin_bit_cast(unsigned, f);
    u += 0x7FFFu + ((u >> 16) & 1u);            // RNE
    return (unsigned short)(u >> 16);
}
__device__ inline unsigned pk(float a, float b) {
    return (unsigned)f2bf(a) | ((unsigned)f2bf(b) << 16);
}

#define WF_N (9 * COUT * KF)               // 46080 = 90 frags * 64 lanes * 8
#define LDS_BYTES (NCH * FROWS * PPW * 16) // 126720 B feature store

// ONE kernel, zero cross-block deps. Block = 4 output rows of one image,
// 1024 thr = 16 waves (1 block/CU).
//  P0: every block redundantly folds ALL weights -> global wfl (identical
//      values; block reads only its own-written data after barrier).
//  P1: features for 6 padded rows into LDS, chunk-major [20][6][66][8].
//  barrier (drains P0 stores + P1 LDS writes)
//  P2: MFMA gemm; B from LDS (2-way free), A from global wfl (L1/L2-hot,
//      fragment-linear 1KB coalesced loads). No other barriers.
__global__ __launch_bounds__(1024, 4) void kan_fused(const float* __restrict__ x,
                                                     const float* __restrict__ w,
                                                     const float* __restrict__ c,
                                                     unsigned short* __restrict__ wfl,
                                                     float* __restrict__ out) {
    extern __shared__ __align__(16) unsigned short lds[];

    const int bid = blockIdx.x;
    const int b   = bid >> 4;            // image
    const int y0  = (bid & 15) * 4;      // first output row
    const int tid = threadIdx.x;

    // ---- P0: redundant weight fold (5760 x 16B chunks; ~5.6 chunks/thread) ----
    // wfl[frag*512 + lane*8 + e] = Wf[shift][o=f*16+(lane&15)][kel=st*32+(lane>>4)*8+e]
    for (int ch = tid; ch < 90 * 64; ch += 1024) {
        const int frag = ch >> 6, lane = ch & 63;
        const int shift = frag / 10, r = frag % 10;
        const int st = r >> 1, f = r & 1;
        const int o = f * 16 + (lane & 15);
        const int kbase = st * 32 + (lane >> 4) * 8;
        unsigned short vals[8];
#pragma unroll
        for (int e = 0; e < 8; ++e) {
            const int kel = kbase + e;
            const int i = kel / 10, n = kel % 10;
            float val = 0.f;
            if (n != 9) {
                const float wv = w[(size_t)(i * COUT + o) * 9 + shift];
                val = (n == 0) ? wv : wv * c[((size_t)(i * COUT + o) * 9 + shift) * NB + (n - 1)];
            }
            vals[e] = f2bf(val);
        }
        *(uint4*)&wfl[ch * 8] = *(const uint4*)vals;
    }

    // ---- P1: features for 6 padded rows into LDS (1584 items, 2 iters) ----
    // item = cg*396 + lr*66 + px ; feature chunk (cg*5+q) at [c][lr][px][8]
    for (int item = tid; item < 4 * FROWS * PPW; item += 1024) {
        const int cg  = item / (FROWS * PPW);
        const int rem = item - cg * (FROWS * PPW);
        const int lr  = rem / PPW;
        const int px  = rem - lr * PPW;
        const int iy  = y0 + lr - 1;     // image row for this padded row

        unsigned rw[20];
        const bool valid = (iy >= 0) & (iy < 64) & (px >= 1) & (px <= 64);
        if (valid) {
            const int ix = px - 1;
#pragma unroll
            for (int j = 0; j < 4; ++j) {
                const int i = cg * 4 + j;
                const float v  = x[((size_t)(b * CIN + i)) * HW + iy * 64 + ix];
                const float p  = __expf(-v);
                const float p2 = p * p;
                const float s  = v * __builtin_amdgcn_rcpf(1.f + p);           // silu
                const float u  = (1.f - p2) * __builtin_amdgcn_rcpf(1.f + p2); // tanh
                const float u2 = 2.f * u;
                const float t1 = u;
                const float t2 = u2 * u - 1.f;
                const float t3 = u2 * t2 - t1;
                const float t4 = u2 * t3 - t2;
                const float t5 = u2 * t4 - t3;
                const float t6 = u2 * t5 - t4;
                const float t7 = u2 * t6 - t5;
                const float t8 = u2 * t7 - t6;
                rw[j * 5 + 0] = pk(s, t1);
                rw[j * 5 + 1] = pk(t2, t3);
                rw[j * 5 + 2] = pk(t4, t5);
                rw[j * 5 + 3] = pk(t6, t7);
                rw[j * 5 + 4] = (unsigned)f2bf(t8);   // hi half 0 (pad feature)
            }
        } else {
#pragma unroll
            for (int j = 0; j < 20; ++j) rw[j] = 0u;
        }
#pragma unroll
        for (int q = 0; q < 5; ++q)
            *(uint4*)&lds[(((cg * 5 + q) * FROWS + lr) * PPW + px) * 8] =
                make_uint4(rw[4 * q], rw[4 * q + 1], rw[4 * q + 2], rw[4 * q + 3]);
    }

    __syncthreads();                     // the ONLY barrier

    // ---- P2: MFMA gemm ----
    const int l   = tid & 63;
    const int wv  = tid >> 6;            // 0..15
    const int ry  = wv >> 2;             // row within block
    const int x0  = (wv & 3) * 16;
    const int col = l & 15;
    const int quad = l >> 4;

    const unsigned short* abase = wfl + l * 8;   // lane-linear A from global

    f32x4 acc0 = {0.f, 0.f, 0.f, 0.f};
    f32x4 acc1 = {0.f, 0.f, 0.f, 0.f};

#pragma unroll
    for (int shift = 0; shift < 9; ++shift) {
        const int dy = shift / 3 - 1, dx = shift % 3 - 1;
        const int lr = ry + 1 + dy;                  // padded row within block
        const int px = x0 + col + 1 + dx;
        // chunk-major B in LDS: chunk = st*4 + quad
        const unsigned short* bb = lds + ((quad * FROWS + lr) * PPW + px) * 8;
#pragma unroll
        for (int st = 0; st < 5; ++st) {
            const bf16x8 bf = *(const bf16x8*)(bb + (size_t)st * 4 * FROWS * PPW * 8);
            const bf16x8 a0 = *(const bf16x8*)(abase + ((shift * 5 + st) * 2) * 512);
            const bf16x8 a1 = *(const bf16x8*)(abase + ((shift * 5 + st) * 2 + 1) * 512);
            acc0 = __builtin_amdgcn_mfma_f32_16x16x32_bf16(a0, bf, acc0, 0, 0, 0);
            acc1 = __builtin_amdgcn_mfma_f32_16x16x32_bf16(a1, bf, acc1, 0, 0, 0);
        }
    }

    float* op = out + (size_t)b * COUT * HW + (y0 + ry) * 64 + x0 + col;
#pragma unroll
    for (int r = 0; r < 4; ++r) {
        op[(size_t)(quad * 4 + r) * HW]      = acc0[r];
        op[(size_t)(quad * 4 + r + 16) * HW] = acc1[r];
    }
}

extern "C" void kernel_launch(void* const* d_in, const int* in_sizes, int n_in,
                              void* d_out, int out_size, void* d_ws, size_t ws_size,
                              hipStream_t stream) {
    const float* x = (const float*)d_in[0];
    const float* w = (const float*)d_in[1];
    const float* c = (const float*)d_in[2];
    float* out = (float*)d_out;

    unsigned short* wfl = (unsigned short*)d_ws;     // 92160 B folded weights

    hipFuncSetAttribute((const void*)kan_fused,
                        hipFuncAttributeMaxDynamicSharedMemorySize, LDS_BYTES);

    kan_fused<<<256, 1024, LDS_BYTES, stream>>>(x, w, c, wfl, out);
}

// Round 17
// 33.840 us; speedup vs baseline: 1.8199x; 1.8199x over previous
//
#include <hip/hip_runtime.h>

#define CIN 16
#define COUT 32
#define NB 8
#define HW 4096
#define PPW 66                 // padded image width
#define PPA (66 * 66)          // padded pixels per image
#define KF 160                 // features per pixel: 16ch * 10 (silu, T1..T8, zero)
#define NCH 20                 // 16B chunks per pixel (KF/8)

typedef short bf16x8 __attribute__((ext_vector_type(8)));
typedef float f32x16 __attribute__((ext_vector_type(16)));

__device__ inline unsigned short f2bf(float f) {
    unsigned u = __builtin_bit_cast(unsigned, f);
    u += 0x7FFFu + ((u >> 16) & 1u);            // RNE
    return (unsigned short)(u >> 16);
}
__device__ inline unsigned pk(float a, float b) {
    return (unsigned)f2bf(a) | ((unsigned)f2bf(b) << 16);
}

#define FEAT_N4 (16 * 4 * PPA)            // 278784 threads: (b, cg, pp), 4 channels each
#define FB4 ((FEAT_N4 + 255) / 256)       // 1089 blocks
#define WF_N (9 * COUT * KF)              // 46080 = 90 frags * 64 lanes * 8
#define WB ((WF_N + 255) / 256)           // 180 blocks

// ---------- Prep: features chunk-major g2t[b][c][pp][8] + 32x32-frag-linear weights ----------
// wfl (r9 mapping): frag = shift*10 + st (st = K16 step);
//   wfl[frag*512 + lane*8 + e] = Wf[shift][o = lane&31][kel = st*16 + (lane>>5)*8 + e]
__global__ __launch_bounds__(256) void kan_prep(const float* __restrict__ x,
                                                const float* __restrict__ w,
                                                const float* __restrict__ c,
                                                unsigned short* __restrict__ g2t,
                                                unsigned short* __restrict__ wfl) {
    if (blockIdx.x < FB4) {
        const int t = blockIdx.x * 256 + threadIdx.x;
        if (t >= FEAT_N4) return;
        const int pp = t % PPA;           // fastest -> coalesced stores
        const int bc = t / PPA;
        const int cg = bc & 3;
        const int b  = bc >> 2;
        const int py = pp / PPW;
        const int px = pp - py * PPW;

        unsigned rw[20];
        const bool interior = (py >= 1) & (py <= 64) & (px >= 1) & (px <= 64);
        if (interior) {
            const int pix = (py - 1) * 64 + (px - 1);
#pragma unroll
            for (int j = 0; j < 4; ++j) {
                const int i = cg * 4 + j;
                const float v  = x[((size_t)(b * CIN + i)) * HW + pix];
                const float p  = __expf(-v);
                const float p2 = p * p;
                const float s  = v * __builtin_amdgcn_rcpf(1.f + p);           // silu
                const float u  = (1.f - p2) * __builtin_amdgcn_rcpf(1.f + p2); // tanh
                const float u2 = 2.f * u;
                const float t1 = u;
                const float t2 = u2 * u - 1.f;
                const float t3 = u2 * t2 - t1;
                const float t4 = u2 * t3 - t2;
                const float t5 = u2 * t4 - t3;
                const float t6 = u2 * t5 - t4;
                const float t7 = u2 * t6 - t5;
                const float t8 = u2 * t7 - t6;
                rw[j * 5 + 0] = pk(s, t1);
                rw[j * 5 + 1] = pk(t2, t3);
                rw[j * 5 + 2] = pk(t4, t5);
                rw[j * 5 + 3] = pk(t6, t7);
                rw[j * 5 + 4] = (unsigned)f2bf(t8);   // hi half 0 (pad feature)
            }
        } else {
#pragma unroll
            for (int j = 0; j < 20; ++j) rw[j] = 0u;
        }
        uint4* dst = (uint4*)g2t;
#pragma unroll
        for (int q = 0; q < 5; ++q)
            dst[((size_t)(b * NCH + cg * 5 + q)) * PPA + pp] =
                make_uint4(rw[4 * q], rw[4 * q + 1], rw[4 * q + 2], rw[4 * q + 3]);
    } else {
        const int t = (blockIdx.x - FB4) * 256 + threadIdx.x;
        if (t >= WF_N) return;
        const int e    = t & 7;
        const int lane = (t >> 3) & 63;
        const int frag = t >> 9;              // 0..89 = shift*10 + st
        const int shift = frag / 10;
        const int st    = frag % 10;
        const int o     = lane & 31;
        const int kel   = st * 16 + (lane >> 5) * 8 + e;
        const int i     = kel / 10, n = kel % 10;
        float val = 0.f;
        if (n != 9) {
            const float wv = w[(size_t)(i * COUT + o) * 9 + shift];
            val = (n == 0) ? wv : wv * c[((size_t)(i * COUT + o) * 9 + shift) * NB + (n - 1)];
        }
        wfl[t] = f2bf(val);
    }
}

// ---------- MFMA GEMM: 32x32x16 tile, K-split wave pairs, single 92KB stage ----------
// 256 blocks x 1024 thr = 1 block/CU, 16 waves/CU. 8 pairs/block; pair pg owns
// 32px x 32cout at (row rg*4 + (pg>>1), x0 = (pg&1)*32); even wave does even
// K16-steps, odd wave odd steps; LDS pair-reduce then even wave stores.
#define W_SHORTS (90 * 512)                          // 46080 shorts = 92160 B
#define LDS_BYTES (W_SHORTS * 2 + 8 * 1024 * 4)      // + 32KB reduce = 124928 B

__global__ __launch_bounds__(1024, 4) void kan_gemm(const unsigned short* __restrict__ g2t,
                                                    const unsigned short* __restrict__ wfl,
                                                    float* __restrict__ out) {
    extern __shared__ __align__(16) unsigned short lds[];

    const int bid = blockIdx.x;
    const int blk = ((bid & 7) << 5) | (bid >> 3);   // XCD x gets images {2x, 2x+1}
    const int b   = blk >> 4;
    const int rg  = blk & 15;
    const int tid = threadIdx.x;
    const int l   = tid & 63;
    const int wv  = tid >> 6;            // 0..15
    const int pg  = wv >> 1;             // pair 0..7
    const int par = wv & 1;              // K-parity
    const int y   = rg * 4 + (pg >> 1);
    const int x0  = (pg & 1) * 32;
    const int colp = l & 31;
    const int hi   = l >> 5;

    // one-shot weight stage: 5760 x 16B, coalesced
    for (int ch = tid; ch < 90 * 64; ch += 1024)
        *(uint4*)&lds[ch * 8] = *(const uint4*)&wfl[ch * 8];
    __syncthreads();

    const unsigned short* abase = lds + l * 8;   // lane-linear A reads (conflict-free)

    f32x16 acc;
#pragma unroll
    for (int r = 0; r < 16; ++r) acc[r] = 0.f;

#pragma unroll
    for (int shift = 0; shift < 9; ++shift) {
        const int dy = shift / 3 - 1, dx = shift % 3 - 1;
        const int pp = (y + 1 + dy) * PPW + (x0 + colp + 1 + dx);
        // K16-step s16 = 2t + par; chunk = 2*s16 + hi = 4t + 2*par + hi
        const unsigned short* bq = g2t + ((size_t)(b * NCH + 2 * par + hi) * PPA + pp) * 8;
        const unsigned short* aq = abase + (shift * 10 + par) * 512;
#pragma unroll
        for (int t = 0; t < 5; ++t) {
            const bf16x8 bf = *(const bf16x8*)(bq + (size_t)(4 * t) * PPA * 8);
            const bf16x8 av = *(const bf16x8*)(aq + (2 * t) * 512);
            acc = __builtin_amdgcn_mfma_f32_32x32x16_bf16(av, bf, acc, 0, 0, 0);
        }
    }

    // ---- pair reduce (separate 32KB area; weights untouched until all waves pass barrier) ----
    float* red = (float*)(lds + W_SHORTS);
    if (par) {
#pragma unroll
        for (int r = 0; r < 16; ++r) red[pg * 1024 + r * 64 + l] = acc[r];
    }
    __syncthreads();
    if (!par) {
        float* op = out + (size_t)b * COUT * HW + y * 64 + x0 + colp;
#pragma unroll
        for (int r = 0; r < 16; ++r) {
            const float v = acc[r] + red[pg * 1024 + r * 64 + l];
            const int o = (r & 3) + 8 * (r >> 2) + 4 * hi;   // D row mapping [m74/m101, r9-verified]
            op[(size_t)o * HW] = v;
        }
    }
}

extern "C" void kernel_launch(void* const* d_in, const int* in_sizes, int n_in,
                              void* d_out, int out_size, void* d_ws, size_t ws_size,
                              hipStream_t stream) {
    const float* x = (const float*)d_in[0];
    const float* w = (const float*)d_in[1];
    const float* c = (const float*)d_in[2];
    float* out = (float*)d_out;

    unsigned short* g2t = (unsigned short*)d_ws;                       // 22.3 MB
    unsigned short* wfl = (unsigned short*)((char*)d_ws + (size_t)16 * PPA * KF * 2);

    hipFuncSetAttribute((const void*)kan_gemm,
                        hipFuncAttributeMaxDynamicSharedMemorySize, LDS_BYTES);

    kan_prep<<<FB4 + WB, 256, 0, stream>>>(x, w, c, g2t, wfl);
    kan_gemm<<<256, 1024, LDS_BYTES, stream>>>(g2t, wfl, out);
}

// Round 18
// 25.524 us; speedup vs baseline: 2.4128x; 1.3258x over previous
//
#include <hip/hip_runtime.h>

#define CIN 16
#define COUT 32
#define NB 8
#define HW 4096
#define PPW 66                 // padded row width (64 + ring)
#define KF 160                 // features per pixel: 16ch * 10 (silu, T1..T8, zero)
#define NCH 20                 // 16B chunks per pixel
#define FROWS 6                // feature rows per block (4 output rows + halo)
#define PLANE 397              // padded chunk-plane stride in 16B units (6*66=396 +1)

typedef short bf16x8 __attribute__((ext_vector_type(8)));
typedef float f32x4 __attribute__((ext_vector_type(4)));

__device__ inline unsigned short f2bf(float f) {
    unsigned u = __builtin_bit_cast(unsigned, f);
    u += 0x7FFFu + ((u >> 16) & 1u);            // RNE
    return (unsigned short)(u >> 16);
}
__device__ inline unsigned pk(float a, float b) {
    return (unsigned)f2bf(a) | ((unsigned)f2bf(b) << 16);
}

#define WF_N (9 * COUT * KF)               // 46080 = 90 frags * 64 lanes * 8
#define LDS_BYTES (NCH * PLANE * 16)       // 127040 B feature store

// ---------- Tiny weight fold: fragment-linear wfl (r15 mapping), 90 blocks ----------
// frag = (shift*5 + st)*2 + f; wfl[frag*512 + lane*8 + e] =
//   Wf[shift][o = f*16 + (lane&15)][kel = st*32 + (lane>>4)*8 + e]
__global__ __launch_bounds__(512) void kan_wf(const float* __restrict__ w,
                                              const float* __restrict__ c,
                                              unsigned short* __restrict__ wfl) {
    const int t = blockIdx.x * 512 + threadIdx.x;   // 90*512 = 46080 exactly
    const int e    = t & 7;
    const int lane = (t >> 3) & 63;
    const int frag = t >> 9;              // 0..89
    const int shift = frag / 10;
    const int r     = frag % 10;
    const int st    = r >> 1;
    const int f     = r & 1;
    const int o     = f * 16 + (lane & 15);
    const int kel   = st * 32 + (lane >> 4) * 8 + e;
    const int i     = kel / 10, n = kel % 10;
    float val = 0.f;
    if (n != 9) {
        const float wv = w[(size_t)(i * COUT + o) * 9 + shift];
        val = (n == 0) ? wv : wv * c[((size_t)(i * COUT + o) * 9 + shift) * NB + (n - 1)];
    }
    wfl[t] = f2bf(val);
}

// ---------- Fused main: features -> LDS (halo recompute), MFMA with B-from-LDS ----------
// 256 blocks x 1024 thr = 1 block/CU, 16 waves. Block = 4 output rows of one image.
// P1: 6 padded rows x 20 chunks into LDS [c][PLANE] (padded stride: ~2-way banks).
// barrier. P2: 16 waves x (16px x 32cout); B ds_read_b128 (~12cyc), A from global
// wfl (static addrs, L1/L2-hot, deep prefetch). One barrier total.
__global__ __launch_bounds__(1024, 4) void kan_main(const float* __restrict__ x,
                                                    const unsigned short* __restrict__ wfl,
                                                    float* __restrict__ out) {
    extern __shared__ __align__(16) unsigned short lds[];

    const int bid = blockIdx.x;
    const int b   = bid >> 4;            // image
    const int y0  = (bid & 15) * 4;      // first output row
    const int tid = threadIdx.x;

    // ---- P1: features (1584 items: 4 cg x 6 lr x 66 px) ----
    for (int item = tid; item < 4 * FROWS * PPW; item += 1024) {
        const int cg  = item / (FROWS * PPW);
        const int rem = item - cg * (FROWS * PPW);
        const int lr  = rem / PPW;
        const int px  = rem - lr * PPW;
        const int iy  = y0 + lr - 1;

        unsigned rw[20];
        const bool valid = (iy >= 0) & (iy < 64) & (px >= 1) & (px <= 64);
        if (valid) {
            const int ix = px - 1;
#pragma unroll
            for (int j = 0; j < 4; ++j) {
                const int i = cg * 4 + j;
                const float v  = x[((size_t)(b * CIN + i)) * HW + iy * 64 + ix];
                const float p  = __expf(-v);
                const float p2 = p * p;
                const float s  = v * __builtin_amdgcn_rcpf(1.f + p);           // silu
                const float u  = (1.f - p2) * __builtin_amdgcn_rcpf(1.f + p2); // tanh
                const float u2 = 2.f * u;
                const float t1 = u;
                const float t2 = u2 * u - 1.f;
                const float t3 = u2 * t2 - t1;
                const float t4 = u2 * t3 - t2;
                const float t5 = u2 * t4 - t3;
                const float t6 = u2 * t5 - t4;
                const float t7 = u2 * t6 - t5;
                const float t8 = u2 * t7 - t6;
                rw[j * 5 + 0] = pk(s, t1);
                rw[j * 5 + 1] = pk(t2, t3);
                rw[j * 5 + 2] = pk(t4, t5);
                rw[j * 5 + 3] = pk(t6, t7);
                rw[j * 5 + 4] = (unsigned)f2bf(t8);   // hi half 0 (pad feature)
            }
        } else {
#pragma unroll
            for (int j = 0; j < 20; ++j) rw[j] = 0u;
        }
        const int base = lr * PPW + px;
#pragma unroll
        for (int q = 0; q < 5; ++q)
            *(uint4*)&lds[((cg * 5 + q) * PLANE + base) * 8] =
                make_uint4(rw[4 * q], rw[4 * q + 1], rw[4 * q + 2], rw[4 * q + 3]);
    }

    __syncthreads();                     // the ONLY barrier

    // ---- P2: MFMA gemm ----
    const int l   = tid & 63;
    const int wv  = tid >> 6;            // 0..15
    const int ry  = wv >> 2;             // row within block
    const int x0  = (wv & 3) * 16;
    const int col = l & 15;
    const int quad = l >> 4;

    const unsigned short* abase = wfl + l * 8;   // lane-linear A from global (static addrs)

    f32x4 acc0 = {0.f, 0.f, 0.f, 0.f};
    f32x4 acc1 = {0.f, 0.f, 0.f, 0.f};

#pragma unroll
    for (int shift = 0; shift < 9; ++shift) {
        const int dy = shift / 3 - 1, dx = shift % 3 - 1;
        const int base = (ry + 1 + dy) * PPW + (x0 + col + 1 + dx);
        // B chunk = st*4 + quad at padded plane stride (bank-spread)
        const unsigned short* bb = lds + (quad * PLANE + base) * 8;
#pragma unroll
        for (int st = 0; st < 5; ++st) {
            const bf16x8 bf = *(const bf16x8*)(bb + (size_t)(st * 4) * PLANE * 8);
            const bf16x8 a0 = *(const bf16x8*)(abase + ((shift * 5 + st) * 2) * 512);
            const bf16x8 a1 = *(const bf16x8*)(abase + ((shift * 5 + st) * 2 + 1) * 512);
            acc0 = __builtin_amdgcn_mfma_f32_16x16x32_bf16(a0, bf, acc0, 0, 0, 0);
            acc1 = __builtin_amdgcn_mfma_f32_16x16x32_bf16(a1, bf, acc1, 0, 0, 0);
        }
    }

    float* op = out + (size_t)b * COUT * HW + (y0 + ry) * 64 + x0 + col;
#pragma unroll
    for (int r = 0; r < 4; ++r) {
        op[(size_t)(quad * 4 + r) * HW]      = acc0[r];
        op[(size_t)(quad * 4 + r + 16) * HW] = acc1[r];
    }
}

extern "C" void kernel_launch(void* const* d_in, const int* in_sizes, int n_in,
                              void* d_out, int out_size, void* d_ws, size_t ws_size,
                              hipStream_t stream) {
    const float* x = (const float*)d_in[0];
    const float* w = (const float*)d_in[1];
    const float* c = (const float*)d_in[2];
    float* out = (float*)d_out;

    unsigned short* wfl = (unsigned short*)d_ws;     // 92160 B folded weights

    hipFuncSetAttribute((const void*)kan_main,
                        hipFuncAttributeMaxDynamicSharedMemorySize, LDS_BYTES);

    kan_wf<<<90, 512, 0, stream>>>(w, c, wfl);
    kan_main<<<256, 1024, LDS_BYTES, stream>>>(x, wfl, out);
}

// Round 19
// 21.252 us; speedup vs baseline: 2.8979x; 1.2010x over previous
//
#include <hip/hip_runtime.h>

#define CIN 16
#define COUT 32
#define NB 8
#define HW 4096
#define PPW 66                 // padded row width (64 + ring)
#define KF 160                 // features per pixel: 16ch * 10 (silu, T1..T8, zero)
#define NCH 20                 // 16B chunks per pixel
#define FROWS 6                // feature rows per block (4 output rows + halo)
#define PLANE 397              // padded chunk-plane stride in 16B units (6*66 + 1)

typedef short bf16x8 __attribute__((ext_vector_type(8)));
typedef float f32x16 __attribute__((ext_vector_type(16)));

__device__ inline unsigned short f2bf(float f) {
    unsigned u = __builtin_bit_cast(unsigned, f);
    u += 0x7FFFu + ((u >> 16) & 1u);            // RNE
    return (unsigned short)(u >> 16);
}
__device__ inline unsigned pk(float a, float b) {
    return (unsigned)f2bf(a) | ((unsigned)f2bf(b) << 16);
}

#define FEAT_SHORTS (NCH * PLANE * 8)          // 63520 shorts = 127040 B
#define LDS_BYTES (FEAT_SHORTS * 2 + 8 * 1024 * 4)   // + 32KB pair-reduce = 159808 B

// ---------- Tiny weight fold: 32x32-fragment-linear wfl (r9/r17 mapping) ----------
// frag = shift*10 + st (st = K16 step);
//   wfl[frag*512 + lane*8 + e] = Wf[shift][o = lane&31][kel = st*16 + (lane>>5)*8 + e]
__global__ __launch_bounds__(512) void kan_wf(const float* __restrict__ w,
                                              const float* __restrict__ c,
                                              unsigned short* __restrict__ wfl) {
    const int t = blockIdx.x * 512 + threadIdx.x;   // 90*512 = 46080 exactly
    const int e    = t & 7;
    const int lane = (t >> 3) & 63;
    const int frag = t >> 9;              // 0..89
    const int shift = frag / 10;
    const int st    = frag % 10;
    const int o     = lane & 31;
    const int kel   = st * 16 + (lane >> 5) * 8 + e;
    const int i     = kel / 10, n = kel % 10;
    float val = 0.f;
    if (n != 9) {
        const float wv = w[(size_t)(i * COUT + o) * 9 + shift];
        val = (n == 0) ? wv : wv * c[((size_t)(i * COUT + o) * 9 + shift) * NB + (n - 1)];
    }
    wfl[t] = f2bf(val);
}

// ---------- Fused main: features -> LDS, 32x32x16 MFMA, K-split wave pairs ----------
// 256 blocks x 1024 thr = 1 block/CU, 16 waves. Block = 4 output rows of one image.
// P1: 6 padded rows x 20 chunks -> LDS [c][PLANE] (r18, unchanged). barrier.
// P2: 8 pairs; pair pg owns 32px x 32cout at (ry=pg>>1, x0=(pg&1)*32); wave parity
// does even/odd K16-steps. A global (1KB static loads, 4x less L2 traffic than r18),
// B ds_read_b128 (serves 32px). LDS pair-reduce, even wave stores.
__global__ __launch_bounds__(1024, 4) void kan_main(const float* __restrict__ x,
                                                    const unsigned short* __restrict__ wfl,
                                                    float* __restrict__ out) {
    extern __shared__ __align__(16) unsigned short lds[];

    const int bid = blockIdx.x;
    const int b   = bid >> 4;            // image
    const int y0  = (bid & 15) * 4;      // first output row
    const int tid = threadIdx.x;

    // ---- P1: features (1584 items: 4 cg x 6 lr x 66 px) — r18 verbatim ----
    for (int item = tid; item < 4 * FROWS * PPW; item += 1024) {
        const int cg  = item / (FROWS * PPW);
        const int rem = item - cg * (FROWS * PPW);
        const int lr  = rem / PPW;
        const int px  = rem - lr * PPW;
        const int iy  = y0 + lr - 1;

        unsigned rw[20];
        const bool valid = (iy >= 0) & (iy < 64) & (px >= 1) & (px <= 64);
        if (valid) {
            const int ix = px - 1;
#pragma unroll
            for (int j = 0; j < 4; ++j) {
                const int i = cg * 4 + j;
                const float v  = x[((size_t)(b * CIN + i)) * HW + iy * 64 + ix];
                const float p  = __expf(-v);
                const float p2 = p * p;
                const float s  = v * __builtin_amdgcn_rcpf(1.f + p);           // silu
                const float u  = (1.f - p2) * __builtin_amdgcn_rcpf(1.f + p2); // tanh
                const float u2 = 2.f * u;
                const float t1 = u;
                const float t2 = u2 * u - 1.f;
                const float t3 = u2 * t2 - t1;
                const float t4 = u2 * t3 - t2;
                const float t5 = u2 * t4 - t3;
                const float t6 = u2 * t5 - t4;
                const float t7 = u2 * t6 - t5;
                const float t8 = u2 * t7 - t6;
                rw[j * 5 + 0] = pk(s, t1);
                rw[j * 5 + 1] = pk(t2, t3);
                rw[j * 5 + 2] = pk(t4, t5);
                rw[j * 5 + 3] = pk(t6, t7);
                rw[j * 5 + 4] = (unsigned)f2bf(t8);   // hi half 0 (pad feature)
            }
        } else {
#pragma unroll
            for (int j = 0; j < 20; ++j) rw[j] = 0u;
        }
        const int base = lr * PPW + px;
#pragma unroll
        for (int q = 0; q < 5; ++q)
            *(uint4*)&lds[((cg * 5 + q) * PLANE + base) * 8] =
                make_uint4(rw[4 * q], rw[4 * q + 1], rw[4 * q + 2], rw[4 * q + 3]);
    }

    __syncthreads();

    // ---- P2: 32x32x16 MFMA, K-parity split ----
    const int l    = tid & 63;
    const int wv   = tid >> 6;           // 0..15
    const int pg   = wv >> 1;            // pair 0..7
    const int par  = wv & 1;             // K16-step parity
    const int ry   = pg >> 1;            // row within block
    const int x0   = (pg & 1) * 32;
    const int colp = l & 31;
    const int hi   = l >> 5;

    const unsigned short* abase = wfl + l * 8;   // lane-linear A from global (static addrs)

    f32x16 acc;
#pragma unroll
    for (int r = 0; r < 16; ++r) acc[r] = 0.f;

#pragma unroll
    for (int shift = 0; shift < 9; ++shift) {
        const int dy = shift / 3 - 1, dx = shift % 3 - 1;
        const int base = (ry + 1 + dy) * PPW + (x0 + colp + 1 + dx);
        const unsigned short* aq = abase + (shift * 10 + par) * 512;
        // K16-step st = 2t + par; B chunk = st*2 + hi = 4t + 2*par + hi
        const unsigned short* bb = lds + ((2 * par + hi) * PLANE + base) * 8;
#pragma unroll
        for (int t = 0; t < 5; ++t) {
            const bf16x8 bf = *(const bf16x8*)(bb + (size_t)(4 * t) * PLANE * 8);
            const bf16x8 av = *(const bf16x8*)(aq + (2 * t) * 512);
            acc = __builtin_amdgcn_mfma_f32_32x32x16_bf16(av, bf, acc, 0, 0, 0);
        }
    }

    // ---- pair reduce (32KB area after features) ----
    float* red = (float*)(lds + FEAT_SHORTS);
    if (par) {
#pragma unroll
        for (int r = 0; r < 16; ++r) red[pg * 1024 + r * 64 + l] = acc[r];
    }
    __syncthreads();
    if (!par) {
        float* op = out + (size_t)b * COUT * HW + (y0 + ry) * 64 + x0 + colp;
#pragma unroll
        for (int r = 0; r < 16; ++r) {
            const float v = acc[r] + red[pg * 1024 + r * 64 + l];
            const int o = (r & 3) + 8 * (r >> 2) + 4 * hi;   // D row mapping [m74/m101, r9/r17-verified]
            op[(size_t)o * HW] = v;
        }
    }
}

extern "C" void kernel_launch(void* const* d_in, const int* in_sizes, int n_in,
                              void* d_out, int out_size, void* d_ws, size_t ws_size,
                              hipStream_t stream) {
    const float* x = (const float*)d_in[0];
    const float* w = (const float*)d_in[1];
    const float* c = (const float*)d_in[2];
    float* out = (float*)d_out;

    unsigned short* wfl = (unsigned short*)d_ws;     // 92160 B folded weights

    hipFuncSetAttribute((const void*)kan_main,
                        hipFuncAttributeMaxDynamicSharedMemorySize, LDS_BYTES);

    kan_wf<<<90, 512, 0, stream>>>(w, c, wfl);
    kan_main<<<256, 1024, LDS_BYTES, stream>>>(x, wfl, out);
}